// Round 1
// 610.993 us; speedup vs baseline: 1.0080x; 1.0080x over previous
//
#include <hip/hip_runtime.h>
#include <hip/hip_bf16.h>
#include <math.h>

typedef __bf16 bf16_t;
typedef __bf16 bf16x4 __attribute__((ext_vector_type(4)));
typedef __bf16 bf16x8 __attribute__((ext_vector_type(8)));
typedef float  f32x4  __attribute__((ext_vector_type(4)));

typedef __attribute__((address_space(1))) const void GVoid;
typedef __attribute__((address_space(3))) void LVoid;

__device__ __forceinline__ void gld16(const void* g, void* l) {
    __builtin_amdgcn_global_load_lds((GVoid*)g, (LVoid*)l, 16, 0, 0);
}

__device__ __forceinline__ float gelu_exact(float v) {
    return 0.5f * v * (1.0f + erff(v * 0.7071067811865475f));
}

// ---------------------------------------------------------------------------
// Tiled transpose + downcast (batched): f32 (R x C) -> bf16 (C x R) per batch.
// ---------------------------------------------------------------------------
__global__ __launch_bounds__(256) void transpose_f32_bf16(
    const float* __restrict__ in, bf16_t* __restrict__ out,
    int R, int C, size_t inBatch, size_t outBatch)
{
    __shared__ bf16_t tile[64][65];
    const float* src = in  + (size_t)blockIdx.z * inBatch;
    bf16_t*      dst = out + (size_t)blockIdx.z * outBatch;
    const int r0 = blockIdx.y * 64, c0 = blockIdx.x * 64;
    const int t = threadIdx.x, tc = t & 63, tr = t >> 6;
#pragma unroll
    for (int i = 0; i < 16; ++i) {
        int r = tr + i * 4;
        tile[r][tc] = (bf16_t)src[(size_t)(r0 + r) * C + c0 + tc];
    }
    __syncthreads();
#pragma unroll
    for (int i = 0; i < 16; ++i) {
        int r = tr + i * 4;
        dst[(size_t)(c0 + r) * R + r0 + tc] = tile[tc][r];
    }
}

// ---------------------------------------------------------------------------
// Tiled bf16 transpose (batched): per-head V (1024x64) -> (64x1024).
// ---------------------------------------------------------------------------
__global__ __launch_bounds__(256) void transpose_bf16(
    const bf16_t* __restrict__ in, bf16_t* __restrict__ out,
    int R, int C, size_t inBatch, size_t outBatch)
{
    __shared__ __align__(16) bf16_t tile[64][65];
    const bf16_t* src = in  + (size_t)blockIdx.z * inBatch;
    bf16_t*       dst = out + (size_t)blockIdx.z * outBatch;
    const int r0 = blockIdx.y * 64, c0 = blockIdx.x * 64;
    const int t = threadIdx.x, tc = t & 63, tr = t >> 6;
#pragma unroll
    for (int i = 0; i < 16; ++i) {
        int r = tr + i * 4;
        tile[r][tc] = src[(size_t)(r0 + r) * C + c0 + tc];
    }
    __syncthreads();
#pragma unroll
    for (int i = 0; i < 16; ++i) {
        int r = tr + i * 4;
        dst[(size_t)(c0 + r) * R + r0 + tc] = tile[tc][r];
    }
}

// ---------------------------------------------------------------------------
// LayerNorm rows of 1024: f32 in -> bf16 out. One 256-thread block / row.
// Vectorized loads (float4) and store (bf16x4).
// ---------------------------------------------------------------------------
__global__ __launch_bounds__(256) void ln_kernel(
    const float* __restrict__ x, const float* __restrict__ g,
    const float* __restrict__ b, bf16_t* __restrict__ out)
{
    const int row = blockIdx.x, t = threadIdx.x;
    const float4 v4 = ((const float4*)(x + (size_t)row * 1024))[t];
    float v[4] = {v4.x, v4.y, v4.z, v4.w};
    float s = v[0] + v[1] + v[2] + v[3];
    float s2 = v[0]*v[0] + v[1]*v[1] + v[2]*v[2] + v[3]*v[3];
#pragma unroll
    for (int o = 1; o < 64; o <<= 1) { s += __shfl_xor(s, o); s2 += __shfl_xor(s2, o); }
    __shared__ float red[8];
    if ((t & 63) == 0) { red[t >> 6] = s; red[4 + (t >> 6)] = s2; }
    __syncthreads();
    s  = red[0] + red[1] + red[2] + red[3];
    s2 = red[4] + red[5] + red[6] + red[7];
    const float mean = s * (1.f / 1024.f);
    const float var  = fmaxf(s2 * (1.f / 1024.f) - mean * mean, 0.f);
    const float rstd = rsqrtf(var + 1e-5f);
    const float4 g4 = ((const float4*)g)[t];
    const float4 b4 = ((const float4*)b)[t];
    bf16x4 o;
    o[0] = (bf16_t)((v[0] - mean) * rstd * g4.x + b4.x);
    o[1] = (bf16_t)((v[1] - mean) * rstd * g4.y + b4.y);
    o[2] = (bf16_t)((v[2] - mean) * rstd * g4.z + b4.z);
    o[3] = (bf16_t)((v[3] - mean) * rstd * g4.w + b4.w);
    *(bf16x4*)(out + (size_t)row * 1024 + t * 4) = o;
}

// ---------------------------------------------------------------------------
// 256x256 / BK=64 / 8-wave 4-phase-per-K-tile GEMM (T2+T3+T4+T5 stack).
//   C(M,N) = A(M,K) @ Bt(N,K)^T  (bf16 in, f32 accumulate)
// Waves: 2(M) x 4(N); per-wave 128x64 output; acc[8][4] f32x4.
// LDS 128 KiB: A dbuf[2] (2 halves of [128][64]), B dbuf[2] same.
// Swizzle: byte ^= (row&7)<<4 within each half; staged via linear
// global_load_lds dest + inverse-swizzled per-lane global source (rule 21).
// Staging for tile t+2 is issued in tile t's register-only phase 4, so the
// per-tile vmcnt(0) only waits on ~4-phase-old loads (counted-vmcnt effect).
// MODE 0: fused QKV (3x1024 segments -> Qo/Ko/Vo + per-seg bias)
// MODE 1: of = acc + b0 + resid     (resid may alias of)
// MODE 2: ob0 = gelu(acc + b0)
// MODE 5: of += acc
// ---------------------------------------------------------------------------
__device__ __forceinline__ bf16x8 lds_rd(const char* base, int rl, int colB) {
    return *(const bf16x8*)(base + rl * 128 + (colB ^ ((rl & 7) << 4)));
}

template <int MODE>
__global__ __launch_bounds__(512, 2) void gemm256(
    const bf16_t* __restrict__ A, const bf16_t* __restrict__ Bt,
    const float* __restrict__ b0, const float* __restrict__ b1,
    const float* __restrict__ b2, const float* resid,
    bf16_t* __restrict__ ob0, bf16_t* __restrict__ ob1,
    bf16_t* __restrict__ ob2, float* of,
    int N, int K)
{
    __shared__ __align__(16) char lds[131072];
    const int t = threadIdx.x;
    const int w = t >> 6, ln = t & 63;
    const int wm = w >> 2, wn = w & 3;
    const int l16 = ln & 15, quad = ln >> 4;
    const int m0 = blockIdx.x * 256, n0 = blockIdx.y * 256;

    const bf16_t* gA = A  + (size_t)m0 * K;
    const bf16_t* gB = Bt + (size_t)n0 * K;

    // staging geometry: virtual tid tt = r2*512 + t covers one [64][64] block;
    // linear LDS slot tt*16 holds logical (row=tt>>3, col=((tt&7)^(row&7))*8)
    const int w1k  = w << 10;
    const int srow = t >> 3;
    const int scol = ((t & 7) ^ (srow & 7)) << 3;

    auto stage = [&](int kt, int dbuf) {
        char* aL = (char*)lds + dbuf * 32768 + w1k;
        char* bL = (char*)lds + 65536 + dbuf * 32768 + w1k;
#pragma unroll
        for (int h = 0; h < 2; ++h) {
#pragma unroll
            for (int r2 = 0; r2 < 2; ++r2) {
                const int row = h * 128 + r2 * 64 + srow;
                gld16(gA + (size_t)row * K + kt + scol, aL + h * 16384 + r2 * 8192);
                gld16(gB + (size_t)row * K + kt + scol, bL + h * 16384 + r2 * 8192);
            }
        }
    };

    f32x4 acc[8][4];
#pragma unroll
    for (int i = 0; i < 8; ++i)
#pragma unroll
        for (int j = 0; j < 4; ++j) acc[i][j] = f32x4{0.f, 0.f, 0.f, 0.f};

    const int ktiles = K >> 6;
    stage(0, 0);
    stage(64, 1);
    asm volatile("s_waitcnt vmcnt(8)" ::: "memory");   // tile 0 landed
    __builtin_amdgcn_s_barrier();
    __builtin_amdgcn_sched_barrier(0);

    bf16x8 af[4][2], bfr[4][2];

    for (int kt = 0; kt < ktiles; ++kt) {
        const int b = kt & 1;
        const char* aB = (const char*)lds + b * 32768 + wm * 16384;
        const char* bB = (const char*)lds + 65536 + b * 32768 + (wn >> 1) * 16384;
        const int bR0 = (wn & 1) << 6;

        // ---- phase 1: ds A rf0-3 + B cf0-1 ; MFMA i<4 x j<2
#pragma unroll
        for (int i = 0; i < 4; ++i)
#pragma unroll
            for (int ks = 0; ks < 2; ++ks)
                af[i][ks] = lds_rd(aB, i * 16 + l16, ks * 64 + quad * 16);
#pragma unroll
        for (int j = 0; j < 2; ++j)
#pragma unroll
            for (int ks = 0; ks < 2; ++ks)
                bfr[j][ks] = lds_rd(bB, bR0 + j * 16 + l16, ks * 64 + quad * 16);
        __builtin_amdgcn_s_setprio(1);
#pragma unroll
        for (int i = 0; i < 4; ++i)
#pragma unroll
            for (int j = 0; j < 2; ++j)
#pragma unroll
                for (int ks = 0; ks < 2; ++ks)
                    acc[i][j] = __builtin_amdgcn_mfma_f32_16x16x32_bf16(
                        af[i][ks], bfr[j][ks], acc[i][j], 0, 0, 0);
        __builtin_amdgcn_s_setprio(0);
        __builtin_amdgcn_sched_barrier(0);
        __builtin_amdgcn_s_barrier();

        // ---- phase 2: ds B cf2-3 ; MFMA i<4 x j=2,3
#pragma unroll
        for (int j = 2; j < 4; ++j)
#pragma unroll
            for (int ks = 0; ks < 2; ++ks)
                bfr[j][ks] = lds_rd(bB, bR0 + j * 16 + l16, ks * 64 + quad * 16);
        __builtin_amdgcn_s_setprio(1);
#pragma unroll
        for (int i = 0; i < 4; ++i)
#pragma unroll
            for (int j = 2; j < 4; ++j)
#pragma unroll
                for (int ks = 0; ks < 2; ++ks)
                    acc[i][j] = __builtin_amdgcn_mfma_f32_16x16x32_bf16(
                        af[i][ks], bfr[j][ks], acc[i][j], 0, 0, 0);
        __builtin_amdgcn_s_setprio(0);
        __builtin_amdgcn_sched_barrier(0);
        __builtin_amdgcn_s_barrier();

        // ---- phase 3: ds A rf4-7 ; MFMA i=4..7 x j=2,3 ; wait + barrier
#pragma unroll
        for (int i = 0; i < 4; ++i)
#pragma unroll
            for (int ks = 0; ks < 2; ++ks)
                af[i][ks] = lds_rd(aB, 64 + i * 16 + l16, ks * 64 + quad * 16);
        __builtin_amdgcn_s_setprio(1);
#pragma unroll
        for (int i = 0; i < 4; ++i)
#pragma unroll
            for (int j = 2; j < 4; ++j)
#pragma unroll
                for (int ks = 0; ks < 2; ++ks)
                    acc[4 + i][j] = __builtin_amdgcn_mfma_f32_16x16x32_bf16(
                        af[i][ks], bfr[j][ks], acc[4 + i][j], 0, 0, 0);
        __builtin_amdgcn_s_setprio(0);
        __builtin_amdgcn_sched_barrier(0);
        // loads being waited on were issued in tile kt-1's phase 4 (~4 phases old)
        asm volatile("s_waitcnt vmcnt(0)" ::: "memory");
        __builtin_amdgcn_s_barrier();
        __builtin_amdgcn_sched_barrier(0);

        // ---- phase 4 (register-only): issue stage(kt+2 -> buf b) ; MFMA i=4..7 x j=0,1
        if (kt + 2 < ktiles) stage((kt + 2) << 6, b);
        __builtin_amdgcn_s_setprio(1);
#pragma unroll
        for (int i = 0; i < 4; ++i)
#pragma unroll
            for (int j = 0; j < 2; ++j)
#pragma unroll
                for (int ks = 0; ks < 2; ++ks)
                    acc[4 + i][j] = __builtin_amdgcn_mfma_f32_16x16x32_bf16(
                        af[i][ks], bfr[j][ks], acc[4 + i][j], 0, 0, 0);
        __builtin_amdgcn_s_setprio(0);
        __builtin_amdgcn_sched_barrier(0);
    }

    // ---- epilogue
#pragma unroll
    for (int i = 0; i < 8; ++i) {
        const int rowb = m0 + wm * 128 + i * 16 + quad * 4;
#pragma unroll
        for (int j = 0; j < 4; ++j) {
            const int col = n0 + wn * 64 + j * 16 + l16;
            if (MODE == 0) {
                const int which = col >> 10;                    // block-uniform
                const float* bias = which == 0 ? b0 : (which == 1 ? b1 : b2);
                bf16_t* outp      = which == 0 ? ob0 : (which == 1 ? ob1 : ob2);
                const int cl = col & 1023;
                const float bc = bias[cl];
#pragma unroll
                for (int r = 0; r < 4; ++r)
                    outp[(size_t)(rowb + r) * 1024 + cl] = (bf16_t)(acc[i][j][r] + bc);
            } else if (MODE == 1) {
                const float bc = b0[col];
#pragma unroll
                for (int r = 0; r < 4; ++r) {
                    const size_t idx = (size_t)(rowb + r) * N + col;
                    of[idx] = acc[i][j][r] + bc + resid[idx];
                }
            } else if (MODE == 2) {
                const float bc = b0[col];
#pragma unroll
                for (int r = 0; r < 4; ++r)
                    ob0[(size_t)(rowb + r) * N + col] =
                        (bf16_t)gelu_exact(acc[i][j][r] + bc);
            } else {
#pragma unroll
                for (int r = 0; r < 4; ++r) {
                    const size_t idx = (size_t)(rowb + r) * N + col;
                    of[idx] += acc[i][j][r];
                }
            }
        }
    }
}

// ---------------------------------------------------------------------------
// Flash attention, conflict-free LDS (K stride 72, V/P stride 136).
// Computes S^T = K.Q^T so P leaves MFMA with 4 consecutive k per lane.
// ---------------------------------------------------------------------------
__global__ __launch_bounds__(256, 2) void attn_kernel(
    const bf16_t* __restrict__ Q, const bf16_t* __restrict__ K,
    const bf16_t* __restrict__ Vt, bf16_t* __restrict__ O)
{
    __shared__ __align__(16) bf16_t smem[26112];
    bf16_t* Vs = smem;             // 64*136
    bf16_t* Ks = smem + 8704;      // 128*72
    bf16_t* Ps = smem + 8704;      // 128*136 (overlays Ks)

    const int t = threadIdx.x;
    const int wv = t >> 6, ln = t & 63;
    const int l16 = ln & 15, quad = ln >> 4;
    const int qt = blockIdx.x, bh = blockIdx.y;
    const size_t hb = (size_t)bh << 16;

    bf16x8 qf[2][2];
#pragma unroll
    for (int rt = 0; rt < 2; ++rt)
#pragma unroll
        for (int ks = 0; ks < 2; ++ks)
            qf[rt][ks] = *(const bf16x8*)(Q + hb +
                (size_t)(qt*128 + wv*32 + rt*16 + l16) * 64 + ks*32 + quad*8);

    float m_run[2] = {-INFINITY, -INFINITY};
    float l_run[2] = {0.f, 0.f};
    f32x4 acc_o[2][4];
#pragma unroll
    for (int rt = 0; rt < 2; ++rt)
#pragma unroll
        for (int dt = 0; dt < 4; ++dt) acc_o[rt][dt] = f32x4{0.f, 0.f, 0.f, 0.f};

    const int krow = t >> 3, kcol = (t & 7) << 3;
    const int vrow = t >> 4, vcol = (t & 15) << 3;
    const float sc = 0.125f;

    for (int j = 0; j < 8; ++j) {
        bf16x8 kg[4], vg[4];
#pragma unroll
        for (int i = 0; i < 4; ++i) {
            kg[i] = *(const bf16x8*)(K  + hb + (size_t)(j*128 + i*32 + krow)*64 + kcol);
            vg[i] = *(const bf16x8*)(Vt + hb + (size_t)(i*16 + vrow)*1024 + j*128 + vcol);
        }
        __syncthreads();
#pragma unroll
        for (int i = 0; i < 4; ++i) {
            *(bf16x8*)(Ks + (i*32 + krow)*72 + kcol)  = kg[i];
            *(bf16x8*)(Vs + (i*16 + vrow)*136 + vcol) = vg[i];
        }
        __syncthreads();

        f32x4 accs[8][2];
#pragma unroll
        for (int nt = 0; nt < 8; ++nt)
#pragma unroll
            for (int rt = 0; rt < 2; ++rt) accs[nt][rt] = f32x4{0.f, 0.f, 0.f, 0.f};
#pragma unroll
        for (int ks = 0; ks < 2; ++ks)
#pragma unroll
            for (int nt = 0; nt < 8; ++nt) {
                bf16x8 kf = *(const bf16x8*)(Ks + (nt*16 + l16)*72 + ks*32 + quad*8);
#pragma unroll
                for (int rt = 0; rt < 2; ++rt)
                    accs[nt][rt] = __builtin_amdgcn_mfma_f32_16x16x32_bf16(
                        kf, qf[rt][ks], accs[nt][rt], 0, 0, 0);
            }

#pragma unroll
        for (int rt = 0; rt < 2; ++rt) {
            float mx = -INFINITY;
#pragma unroll
            for (int nt = 0; nt < 8; ++nt)
#pragma unroll
                for (int r = 0; r < 4; ++r) mx = fmaxf(mx, accs[nt][rt][r]);
            mx *= sc;
            mx = fmaxf(mx, __shfl_xor(mx, 16));
            mx = fmaxf(mx, __shfl_xor(mx, 32));
            const float mnew  = fmaxf(m_run[rt], mx);
            const float alpha = __expf(m_run[rt] - mnew);
            m_run[rt] = mnew;
            float rs = 0.f;
#pragma unroll
            for (int nt = 0; nt < 8; ++nt)
#pragma unroll
                for (int r = 0; r < 4; ++r) {
                    float p = __expf(accs[nt][rt][r] * sc - mnew);
                    accs[nt][rt][r] = p;
                    rs += p;
                }
            rs += __shfl_xor(rs, 16);
            rs += __shfl_xor(rs, 32);
            l_run[rt] = l_run[rt] * alpha + rs;
#pragma unroll
            for (int r = 0; r < 4; ++r) {
                const float af = __shfl(alpha, quad*4 + r, 16);
#pragma unroll
                for (int dt = 0; dt < 4; ++dt) acc_o[rt][dt][r] *= af;
            }
        }

        __syncthreads();
#pragma unroll
        for (int rt = 0; rt < 2; ++rt) {
            const int mrow = wv*32 + rt*16 + l16;
#pragma unroll
            for (int nt = 0; nt < 8; ++nt) {
                bf16x4 pk;
#pragma unroll
                for (int r = 0; r < 4; ++r) pk[r] = (bf16_t)accs[nt][rt][r];
                *(bf16x4*)(Ps + mrow*136 + nt*16 + quad*4) = pk;
            }
        }
#pragma unroll
        for (int ks = 0; ks < 4; ++ks) {
            bf16x8 ap[2];
#pragma unroll
            for (int rt = 0; rt < 2; ++rt)
                ap[rt] = *(const bf16x8*)(Ps + (wv*32 + rt*16 + l16)*136 + ks*32 + quad*8);
#pragma unroll
            for (int dt = 0; dt < 4; ++dt) {
                bf16x8 bvv = *(const bf16x8*)(Vs + (dt*16 + l16)*136 + ks*32 + quad*8);
#pragma unroll
                for (int rt = 0; rt < 2; ++rt)
                    acc_o[rt][dt] = __builtin_amdgcn_mfma_f32_16x16x32_bf16(
                        ap[rt], bvv, acc_o[rt][dt], 0, 0, 0);
            }
        }
    }

    const int b = bh >> 4, h = bh & 15;
#pragma unroll
    for (int rt = 0; rt < 2; ++rt) {
#pragma unroll
        for (int r = 0; r < 4; ++r) {
            const float inv = 1.f / __shfl(l_run[rt], quad*4 + r, 16);
            const int m = qt*128 + wv*32 + rt*16 + quad*4 + r;
#pragma unroll
            for (int dt = 0; dt < 4; ++dt) {
                const int d = dt*16 + l16;
                O[((size_t)b*1024 + m)*1024 + h*64 + d] =
                    (bf16_t)(acc_o[rt][dt][r] * inv);
            }
        }
    }
}

// ---------------------------------------------------------------------------
extern "C" void kernel_launch(void* const* d_in, const int* in_sizes, int n_in,
                              void* d_out, int out_size, void* d_ws, size_t ws_size,
                              hipStream_t stream)
{
    (void)in_sizes; (void)n_in;
    const size_t MB = 1ull << 20;
    if (ws_size < 64 * MB) {
        hipMemsetAsync(d_out, 0, (size_t)out_size * sizeof(float), stream);
        return;
    }

    const float* x  = (const float*)d_in[0];
    const float* g1 = (const float*)d_in[1];
    const float* b1 = (const float*)d_in[2];
    const float* Wq = (const float*)d_in[3];
    const float* bq = (const float*)d_in[4];
    const float* Wk = (const float*)d_in[5];
    const float* bk = (const float*)d_in[6];
    const float* Wv = (const float*)d_in[7];
    const float* bv = (const float*)d_in[8];
    const float* Wp = (const float*)d_in[9];
    const float* bp = (const float*)d_in[10];
    const float* g2 = (const float*)d_in[11];
    const float* b2 = (const float*)d_in[12];
    const float* W1 = (const float*)d_in[13];
    const float* c1 = (const float*)d_in[14];
    const float* W2 = (const float*)d_in[15];
    const float* c2 = (const float*)d_in[16];

    // Workspace (64 MB):
    //   0-16  (S0): Kb            -> hid[0:16MB]
    //   16-32 (S1): Vb -> Ob      -> hid[16:32MB]   (hid = 8192x2048 bf16)
    //   32-48 (S2): h1 -> Vt -> h2
    //   48-54     : WqT|WkT|WvT (QKV fused Bt)  -> W2T (8 MB @48-56, after proj)
    //   54-56     : WpT
    //   56-64     : W1T (4096x1024)
    //   d_out (32 MB f32): Qb bf16 -> x2 f32 -> final out (FC2 RMW in place)
    char* ws = (char*)d_ws;
    bf16_t* Kb  = (bf16_t*)(ws);
    bf16_t* Vb  = (bf16_t*)(ws + 16 * MB);
    bf16_t* Cs  = (bf16_t*)(ws + 32 * MB);
    bf16_t* WqT = (bf16_t*)(ws + 48 * MB);
    bf16_t* WpT = (bf16_t*)(ws + 54 * MB);
    bf16_t* W1T = (bf16_t*)(ws + 56 * MB);
    bf16_t* W2T = (bf16_t*)(ws + 48 * MB);   // after WqkvT/WpT dead
    bf16_t* Qb  = (bf16_t*)d_out;
    bf16_t* Ob  = Vb;
    bf16_t* hid = Kb;                        // 32 MB spanning S0+S1
    bf16_t* h2  = Cs;
    float*  x2  = (float*)d_out;
    float*  outf = (float*)d_out;

    const dim3 blk(256);
    const dim3 blk5(512);

    // weight transposes (f32 -> bf16, (N,K)); Wq/Wk/Wv land contiguous
    transpose_f32_bf16<<<dim3(16, 16, 1), blk, 0, stream>>>(Wq, WqT,              1024, 1024, 0, 0);
    transpose_f32_bf16<<<dim3(16, 16, 1), blk, 0, stream>>>(Wk, WqT + 1024*1024,  1024, 1024, 0, 0);
    transpose_f32_bf16<<<dim3(16, 16, 1), blk, 0, stream>>>(Wv, WqT + 2*1024*1024, 1024, 1024, 0, 0);
    transpose_f32_bf16<<<dim3(16, 16, 1), blk, 0, stream>>>(Wp, WpT,              1024, 1024, 0, 0);
    transpose_f32_bf16<<<dim3(64, 16, 1), blk, 0, stream>>>(W1, W1T,              1024, 4096, 0, 0);

    // LN1: x -> h1 (Cs)
    ln_kernel<<<8192, blk, 0, stream>>>(x, g1, b1, Cs);

    // fused QKV: 384 blocks of 512 thr (256^2 tiles over N=3072)
    gemm256<0><<<dim3(32, 12), blk5, 0, stream>>>(
        Cs, WqT, bq, bk, bv, nullptr, Qb, Kb, Vb, nullptr, 3072, 1024);

    // per-head V transpose: V(S1) -> Vt(S2)
    transpose_bf16<<<dim3(1, 16, 128), blk, 0, stream>>>(Vb, Cs, 1024, 64, 65536, 65536);

    // flash attention: Q(d_out), K(S0), Vt(S2) -> Ob(S1)
    attn_kernel<<<dim3(8, 128), blk, 0, stream>>>(Qb, Kb, Cs, Ob);

    // proj + residual: Ob @ Wp + bp + x -> x2 (f32, d_out)
    gemm256<1><<<dim3(32, 4), blk5, 0, stream>>>(
        Ob, WpT, bp, nullptr, nullptr, x, nullptr, nullptr, nullptr, x2, 1024, 1024);

    // W2 -> 2 K-chunks (1024 x 2048 each), into dead weights arena @48-56
    transpose_f32_bf16<<<dim3(16, 32, 2), blk, 0, stream>>>(
        W2, W2T, 2048, 1024, 2048*1024, 2048*1024);

    // LN2: x2 -> h2 (Cs)
    ln_kernel<<<8192, blk, 0, stream>>>(x2, g2, b2, h2);

    // MLP: 2 K-chunks of 2048; hid = 8192x2048 bf16 (32 MB @ S0+S1)
    for (int c = 0; c < 2; ++c) {
        gemm256<2><<<dim3(32, 8), blk5, 0, stream>>>(
            h2, W1T + (size_t)c * 2048 * 1024, c1 + c * 2048,
            nullptr, nullptr, nullptr, hid, nullptr, nullptr, nullptr, 2048, 1024);
        if (c == 0)
            gemm256<1><<<dim3(32, 4), blk5, 0, stream>>>(
                hid, W2T, c2, nullptr, nullptr, outf,
                nullptr, nullptr, nullptr, outf, 1024, 2048);
        else
            gemm256<5><<<dim3(32, 4), blk5, 0, stream>>>(
                hid, W2T + (size_t)2048 * 1024, nullptr, nullptr, nullptr, nullptr,
                nullptr, nullptr, nullptr, outf, 1024, 2048);
    }
}

// Round 3
// 534.513 us; speedup vs baseline: 1.1522x; 1.1431x over previous
//
#include <hip/hip_runtime.h>
#include <hip/hip_bf16.h>
#include <math.h>

typedef __bf16 bf16_t;
typedef __bf16 bf16x4 __attribute__((ext_vector_type(4)));
typedef __bf16 bf16x8 __attribute__((ext_vector_type(8)));
typedef float  f32x4  __attribute__((ext_vector_type(4)));

typedef __attribute__((address_space(1))) const void GVoid;
typedef __attribute__((address_space(3))) void LVoid;

__device__ __forceinline__ void gld16(const void* g, void* l) {
    __builtin_amdgcn_global_load_lds((GVoid*)g, (LVoid*)l, 16, 0, 0);
}

__device__ __forceinline__ float gelu_exact(float v) {
    return 0.5f * v * (1.0f + erff(v * 0.7071067811865475f));
}

__device__ __forceinline__ f32x4 MF(bf16x8 a, bf16x8 b, f32x4 c) {
    return __builtin_amdgcn_mfma_f32_16x16x32_bf16(a, b, c, 0, 0, 0);
}

#define VMCNT(n) asm volatile("s_waitcnt vmcnt(" #n ")" ::: "memory")
#define FENCE()  asm volatile("" ::: "memory")

// ---------------------------------------------------------------------------
// Tiled transpose + downcast (batched): f32 (R x C) -> bf16 (C x R) per batch.
// ---------------------------------------------------------------------------
__global__ __launch_bounds__(256) void transpose_f32_bf16(
    const float* __restrict__ in, bf16_t* __restrict__ out,
    int R, int C, size_t inBatch, size_t outBatch)
{
    __shared__ bf16_t tile[64][65];
    const float* src = in  + (size_t)blockIdx.z * inBatch;
    bf16_t*      dst = out + (size_t)blockIdx.z * outBatch;
    const int r0 = blockIdx.y * 64, c0 = blockIdx.x * 64;
    const int t = threadIdx.x, tc = t & 63, tr = t >> 6;
#pragma unroll
    for (int i = 0; i < 16; ++i) {
        int r = tr + i * 4;
        tile[r][tc] = (bf16_t)src[(size_t)(r0 + r) * C + c0 + tc];
    }
    __syncthreads();
#pragma unroll
    for (int i = 0; i < 16; ++i) {
        int r = tr + i * 4;
        dst[(size_t)(c0 + r) * R + r0 + tc] = tile[tc][r];
    }
}

// ---------------------------------------------------------------------------
// Tiled bf16 transpose (batched): per-head V (1024x64) -> (64x1024).
// ---------------------------------------------------------------------------
__global__ __launch_bounds__(256) void transpose_bf16(
    const bf16_t* __restrict__ in, bf16_t* __restrict__ out,
    int R, int C, size_t inBatch, size_t outBatch)
{
    __shared__ __align__(16) bf16_t tile[64][65];
    const bf16_t* src = in  + (size_t)blockIdx.z * inBatch;
    bf16_t*       dst = out + (size_t)blockIdx.z * outBatch;
    const int r0 = blockIdx.y * 64, c0 = blockIdx.x * 64;
    const int t = threadIdx.x, tc = t & 63, tr = t >> 6;
#pragma unroll
    for (int i = 0; i < 16; ++i) {
        int r = tr + i * 4;
        tile[r][tc] = src[(size_t)(r0 + r) * C + c0 + tc];
    }
    __syncthreads();
#pragma unroll
    for (int i = 0; i < 16; ++i) {
        int r = tr + i * 4;
        dst[(size_t)(c0 + r) * R + r0 + tc] = tile[tc][r];
    }
}

// ---------------------------------------------------------------------------
// LayerNorm rows of 1024: f32 in -> bf16 out. One 256-thread block / row.
// ---------------------------------------------------------------------------
__global__ __launch_bounds__(256) void ln_kernel(
    const float* __restrict__ x, const float* __restrict__ g,
    const float* __restrict__ b, bf16_t* __restrict__ out)
{
    const int row = blockIdx.x, t = threadIdx.x;
    const float4 v4 = ((const float4*)(x + (size_t)row * 1024))[t];
    float v[4] = {v4.x, v4.y, v4.z, v4.w};
    float s = v[0] + v[1] + v[2] + v[3];
    float s2 = v[0]*v[0] + v[1]*v[1] + v[2]*v[2] + v[3]*v[3];
#pragma unroll
    for (int o = 1; o < 64; o <<= 1) { s += __shfl_xor(s, o); s2 += __shfl_xor(s2, o); }
    __shared__ float red[8];
    if ((t & 63) == 0) { red[t >> 6] = s; red[4 + (t >> 6)] = s2; }
    __syncthreads();
    s  = red[0] + red[1] + red[2] + red[3];
    s2 = red[4] + red[5] + red[6] + red[7];
    const float mean = s * (1.f / 1024.f);
    const float var  = fmaxf(s2 * (1.f / 1024.f) - mean * mean, 0.f);
    const float rstd = rsqrtf(var + 1e-5f);
    const float4 g4 = ((const float4*)g)[t];
    const float4 b4 = ((const float4*)b)[t];
    bf16x4 o;
    o[0] = (bf16_t)((v[0] - mean) * rstd * g4.x + b4.x);
    o[1] = (bf16_t)((v[1] - mean) * rstd * g4.y + b4.y);
    o[2] = (bf16_t)((v[2] - mean) * rstd * g4.z + b4.z);
    o[3] = (bf16_t)((v[3] - mean) * rstd * g4.w + b4.w);
    *(bf16x4*)(out + (size_t)row * 1024 + t * 4) = o;
}

// ---------------------------------------------------------------------------
// 256xBN / BK=64 / 8-wave GEMM with derived-waits pipeline (T2+T3+T4+T5).
//   C(M,N) = A(M,K) @ Bt(N,K)^T, bf16 in, f32 accumulate.
// Strided wave mapping: af[i] rows = i*32+wm*16+l16 (A-h0 = i0-3, A-h1 = i4-7),
// bfr[j] rows = j*64+wn*16+l16 (B-h0 = low j, B-h1 = high j) -> half-tile
// consumption is phase-ordered uniformly: {Ah0,Bh0}@P1, Bh1@P2, Ah1@P3.
// Staging: ONE granule per phase, issued 6-7 phases before use:
//   P1: Bh1(T+1) | P2: Ah0(T+2) | P3: Bh0(T+2) | P4: Ah1(T+2)
// Counted vmcnt gates (never 0 in steady state):
//   BN256: P1 vmcnt(10) [last tile 4], P2 vmcnt(8) [last 0]
//   BN128: P1 vmcnt(8)  [last 3],      P2 vmcnt(6) [last 0]
// Barriers: phase entries P1, P2, P4 (P3's is provably redundant).
// LDS XOR swizzle byte^=((row&7)<<4); linear gld16 dest + inverse-swizzled
// global source + swizzled ds_read (both-sides rule).
// MODE 0: fused QKV   MODE 1: of = acc+b0+resid   MODE 2: ob0 = gelu(acc+b0)
// MODE 5: of += acc
// ---------------------------------------------------------------------------
template <int MODE, int BN>
__global__ __launch_bounds__(512, 2) void gemm256(
    const bf16_t* __restrict__ A, const bf16_t* __restrict__ Bt,
    const float* __restrict__ b0, const float* __restrict__ b1,
    const float* __restrict__ b2, const float* resid,
    bf16_t* __restrict__ ob0, bf16_t* __restrict__ ob1,
    bf16_t* __restrict__ ob2, float* of, int N, int K)
{
    constexpr int NJ   = BN / 64;     // j-blocks: 4 (BN256) or 2 (BN128)
    constexpr int JH   = NJ / 2;      // j per half
    constexpr int BUFB = BN * 128;    // B buf bytes
    constexpr int HBB  = BN * 64;     // B half bytes
    __shared__ __align__(16) char lds[65536 + 2 * BUFB];
    char* ldsB = lds + 65536;

    const int t = threadIdx.x;
    const int w = t >> 6, ln = t & 63;
    const int wm = w & 1, wn = w >> 1;          // 2(M) x 4(N)
    const int l16 = ln & 15, quad = ln >> 4;
    const int m0 = blockIdx.x * 256, n0 = blockIdx.y * BN;

    const bf16_t* gA = A  + (size_t)m0 * K;
    const bf16_t* gB = Bt + (size_t)n0 * K;

    const int w1k  = w << 10;
    const int srow = t >> 3;                        // 0..63
    const int scol = ((t & 7) ^ (srow & 7)) << 3;   // inverse-swizzled col (elems)

    auto stageA = [&](int kt, int h) {
        char* dst = lds + (kt & 1) * 32768 + h * 16384 + w1k;
        const bf16_t* s0 = gA + (size_t)(h * 128 + srow) * K + (kt << 6) + scol;
        gld16(s0, dst);
        gld16(s0 + (size_t)64 * K, dst + 8192);
    };
    auto stageB = [&](int kt, int h) {
        char* dst = ldsB + (kt & 1) * BUFB + h * HBB + w1k;
        if constexpr (BN == 256) {
            const bf16_t* s0 = gB + (size_t)(h * 128 + srow) * K + (kt << 6) + scol;
            gld16(s0, dst);
            gld16(s0 + (size_t)64 * K, dst + 8192);
        } else {
            const bf16_t* s0 = gB + (size_t)(h * 64 + srow) * K + (kt << 6) + scol;
            gld16(s0, dst);
        }
    };

    auto rdA = [&](int q, int i, int ks) -> bf16x8 {
        const int r = (i & 3) * 32 + wm * 16 + l16;          // row within half
        const char* p = lds + q * 32768 + (i >> 2) * 16384 + r * 128
                        + ((ks * 64 + quad * 16) ^ ((r & 7) << 4));
        return *(const bf16x8*)p;
    };
    auto rdB = [&](int q, int j, int ks) -> bf16x8 {
        int half, r;
        if constexpr (BN == 256) { half = j >> 1; r = (j & 1) * 64 + wn * 16 + l16; }
        else                     { half = j;      r = wn * 16 + l16; }
        const char* p = ldsB + q * BUFB + half * HBB + r * 128
                        + ((ks * 64 + quad * 16) ^ ((r & 7) << 4));
        return *(const bf16x8*)p;
    };

    f32x4 acc[8][NJ];
#pragma unroll
    for (int i = 0; i < 8; ++i)
#pragma unroll
        for (int j = 0; j < NJ; ++j) acc[i][j] = f32x4{0.f, 0.f, 0.f, 0.f};

    const int ktiles = K >> 6;

    // prologue: 7 granules in the canonical issue order
    stageA(0, 0); stageB(0, 0); stageA(0, 1); stageB(0, 1);
    stageA(1, 0); stageB(1, 0); stageA(1, 1);

    bf16x8 afr[4][2], bL[JH][2], bH[JH][2];

    for (int T = 0; T < ktiles; ++T) {
        const int q = T & 1;
        const bool notlast = (T + 1 < ktiles);
        const bool st2     = (T + 2 < ktiles);

        // ---------------- phase 1: needs Ah0(T), Bh0(T) ----------------
        if (notlast) { if constexpr (BN == 256) VMCNT(10); else VMCNT(8); }
        else         { if constexpr (BN == 256) VMCNT(4);  else VMCNT(3); }
        __builtin_amdgcn_s_barrier();
        FENCE(); __builtin_amdgcn_sched_barrier(0);
        if (notlast) stageB(T + 1, 1);
#pragma unroll
        for (int i = 0; i < 4; ++i)
#pragma unroll
            for (int ks = 0; ks < 2; ++ks) afr[i][ks] = rdA(q, i, ks);
#pragma unroll
        for (int j = 0; j < JH; ++j)
#pragma unroll
            for (int ks = 0; ks < 2; ++ks) bL[j][ks] = rdB(q, j, ks);
        __builtin_amdgcn_s_setprio(1);
#pragma unroll
        for (int i = 0; i < 4; ++i)
#pragma unroll
            for (int j = 0; j < JH; ++j)
#pragma unroll
                for (int ks = 0; ks < 2; ++ks)
                    acc[i][j] = MF(afr[i][ks], bL[j][ks], acc[i][j]);
        __builtin_amdgcn_s_setprio(0);
        __builtin_amdgcn_sched_barrier(0);

        // ---------------- phase 2: needs Bh1(T) ----------------
        if (notlast) { if constexpr (BN == 256) VMCNT(8); else VMCNT(6); }
        else         VMCNT(0);
        __builtin_amdgcn_s_barrier();
        FENCE(); __builtin_amdgcn_sched_barrier(0);
        if (st2) stageA(T + 2, 0);
#pragma unroll
        for (int j = 0; j < JH; ++j)
#pragma unroll
            for (int ks = 0; ks < 2; ++ks) bH[j][ks] = rdB(q, JH + j, ks);
        __builtin_amdgcn_s_setprio(1);
#pragma unroll
        for (int i = 0; i < 4; ++i)
#pragma unroll
            for (int j = 0; j < JH; ++j)
#pragma unroll
                for (int ks = 0; ks < 2; ++ks)
                    acc[i][JH + j] = MF(afr[i][ks], bH[j][ks], acc[i][JH + j]);
        __builtin_amdgcn_s_setprio(0);
        __builtin_amdgcn_sched_barrier(0);

        // ---------------- phase 3: needs Ah1(T) (already retired) ------
        // (no barrier: P2-entry barrier already separates P1 reads from here)
        if (st2) stageB(T + 2, 0);
#pragma unroll
        for (int i = 0; i < 4; ++i)
#pragma unroll
            for (int ks = 0; ks < 2; ++ks) afr[i][ks] = rdA(q, 4 + i, ks);
        __builtin_amdgcn_s_setprio(1);
#pragma unroll
        for (int i = 0; i < 4; ++i)
#pragma unroll
            for (int j = 0; j < JH; ++j)
#pragma unroll
                for (int ks = 0; ks < 2; ++ks)
                    acc[4 + i][JH + j] = MF(afr[i][ks], bH[j][ks], acc[4 + i][JH + j]);
        __builtin_amdgcn_s_setprio(0);
        __builtin_amdgcn_sched_barrier(0);

        // ---------------- phase 4: register-only MFMA ----------------
        __builtin_amdgcn_s_barrier();      // separates P3 reads from Ah1 stage
        FENCE(); __builtin_amdgcn_sched_barrier(0);
        if (st2) stageA(T + 2, 1);
        __builtin_amdgcn_s_setprio(1);
#pragma unroll
        for (int i = 0; i < 4; ++i)
#pragma unroll
            for (int j = 0; j < JH; ++j)
#pragma unroll
                for (int ks = 0; ks < 2; ++ks)
                    acc[4 + i][j] = MF(afr[i][ks], bL[j][ks], acc[4 + i][j]);
        __builtin_amdgcn_s_setprio(0);
        __builtin_amdgcn_sched_barrier(0);
    }

    // ---- epilogue
#pragma unroll
    for (int i = 0; i < 8; ++i) {
        const int rowb = m0 + i * 32 + wm * 16 + quad * 4;
#pragma unroll
        for (int j = 0; j < NJ; ++j) {
            const int col = n0 + j * 64 + wn * 16 + l16;
            if constexpr (MODE == 0) {
                const int which = col >> 10;                    // block-uniform
                const float* bias = which == 0 ? b0 : (which == 1 ? b1 : b2);
                bf16_t* outp      = which == 0 ? ob0 : (which == 1 ? ob1 : ob2);
                const int cl = col & 1023;
                const float bc = bias[cl];
#pragma unroll
                for (int r = 0; r < 4; ++r)
                    outp[(size_t)(rowb + r) * 1024 + cl] = (bf16_t)(acc[i][j][r] + bc);
            } else if constexpr (MODE == 1) {
                const float bc = b0[col];
#pragma unroll
                for (int r = 0; r < 4; ++r) {
                    const size_t idx = (size_t)(rowb + r) * N + col;
                    of[idx] = acc[i][j][r] + bc + resid[idx];
                }
            } else if constexpr (MODE == 2) {
                const float bc = b0[col];
#pragma unroll
                for (int r = 0; r < 4; ++r)
                    ob0[(size_t)(rowb + r) * N + col] =
                        (bf16_t)gelu_exact(acc[i][j][r] + bc);
            } else {
#pragma unroll
                for (int r = 0; r < 4; ++r) {
                    const size_t idx = (size_t)(rowb + r) * N + col;
                    of[idx] += acc[i][j][r];
                }
            }
        }
    }
}

// ---------------------------------------------------------------------------
// Flash attention, conflict-free LDS (K stride 72, V/P stride 136).
// ---------------------------------------------------------------------------
__global__ __launch_bounds__(256, 2) void attn_kernel(
    const bf16_t* __restrict__ Q, const bf16_t* __restrict__ K,
    const bf16_t* __restrict__ Vt, bf16_t* __restrict__ O)
{
    __shared__ __align__(16) bf16_t smem[26112];
    bf16_t* Vs = smem;             // 64*136
    bf16_t* Ks = smem + 8704;      // 128*72
    bf16_t* Ps = smem + 8704;      // 128*136 (overlays Ks)

    const int t = threadIdx.x;
    const int wv = t >> 6, ln = t & 63;
    const int l16 = ln & 15, quad = ln >> 4;
    const int qt = blockIdx.x, bh = blockIdx.y;
    const size_t hb = (size_t)bh << 16;

    bf16x8 qf[2][2];
#pragma unroll
    for (int rt = 0; rt < 2; ++rt)
#pragma unroll
        for (int ks = 0; ks < 2; ++ks)
            qf[rt][ks] = *(const bf16x8*)(Q + hb +
                (size_t)(qt*128 + wv*32 + rt*16 + l16) * 64 + ks*32 + quad*8);

    float m_run[2] = {-INFINITY, -INFINITY};
    float l_run[2] = {0.f, 0.f};
    f32x4 acc_o[2][4];
#pragma unroll
    for (int rt = 0; rt < 2; ++rt)
#pragma unroll
        for (int dt = 0; dt < 4; ++dt) acc_o[rt][dt] = f32x4{0.f, 0.f, 0.f, 0.f};

    const int krow = t >> 3, kcol = (t & 7) << 3;
    const int vrow = t >> 4, vcol = (t & 15) << 3;
    const float sc = 0.125f;

    for (int j = 0; j < 8; ++j) {
        bf16x8 kg[4], vg[4];
#pragma unroll
        for (int i = 0; i < 4; ++i) {
            kg[i] = *(const bf16x8*)(K  + hb + (size_t)(j*128 + i*32 + krow)*64 + kcol);
            vg[i] = *(const bf16x8*)(Vt + hb + (size_t)(i*16 + vrow)*1024 + j*128 + vcol);
        }
        __syncthreads();
#pragma unroll
        for (int i = 0; i < 4; ++i) {
            *(bf16x8*)(Ks + (i*32 + krow)*72 + kcol)  = kg[i];
            *(bf16x8*)(Vs + (i*16 + vrow)*136 + vcol) = vg[i];
        }
        __syncthreads();

        f32x4 accs[8][2];
#pragma unroll
        for (int nt = 0; nt < 8; ++nt)
#pragma unroll
            for (int rt = 0; rt < 2; ++rt) accs[nt][rt] = f32x4{0.f, 0.f, 0.f, 0.f};
#pragma unroll
        for (int ks = 0; ks < 2; ++ks)
#pragma unroll
            for (int nt = 0; nt < 8; ++nt) {
                bf16x8 kf = *(const bf16x8*)(Ks + (nt*16 + l16)*72 + ks*32 + quad*8);
#pragma unroll
                for (int rt = 0; rt < 2; ++rt)
                    accs[nt][rt] = __builtin_amdgcn_mfma_f32_16x16x32_bf16(
                        kf, qf[rt][ks], accs[nt][rt], 0, 0, 0);
            }

#pragma unroll
        for (int rt = 0; rt < 2; ++rt) {
            float mx = -INFINITY;
#pragma unroll
            for (int nt = 0; nt < 8; ++nt)
#pragma unroll
                for (int r = 0; r < 4; ++r) mx = fmaxf(mx, accs[nt][rt][r]);
            mx *= sc;
            mx = fmaxf(mx, __shfl_xor(mx, 16));
            mx = fmaxf(mx, __shfl_xor(mx, 32));
            const float mnew  = fmaxf(m_run[rt], mx);
            const float alpha = __expf(m_run[rt] - mnew);
            m_run[rt] = mnew;
            float rs = 0.f;
#pragma unroll
            for (int nt = 0; nt < 8; ++nt)
#pragma unroll
                for (int r = 0; r < 4; ++r) {
                    float p = __expf(accs[nt][rt][r] * sc - mnew);
                    accs[nt][rt][r] = p;
                    rs += p;
                }
            rs += __shfl_xor(rs, 16);
            rs += __shfl_xor(rs, 32);
            l_run[rt] = l_run[rt] * alpha + rs;
#pragma unroll
            for (int r = 0; r < 4; ++r) {
                const float af = __shfl(alpha, quad*4 + r, 16);
#pragma unroll
                for (int dt = 0; dt < 4; ++dt) acc_o[rt][dt][r] *= af;
            }
        }

        __syncthreads();
#pragma unroll
        for (int rt = 0; rt < 2; ++rt) {
            const int mrow = wv*32 + rt*16 + l16;
#pragma unroll
            for (int nt = 0; nt < 8; ++nt) {
                bf16x4 pk;
#pragma unroll
                for (int r = 0; r < 4; ++r) pk[r] = (bf16_t)accs[nt][rt][r];
                *(bf16x4*)(Ps + mrow*136 + nt*16 + quad*4) = pk;
            }
        }
#pragma unroll
        for (int ks = 0; ks < 4; ++ks) {
            bf16x8 ap[2];
#pragma unroll
            for (int rt = 0; rt < 2; ++rt)
                ap[rt] = *(const bf16x8*)(Ps + (wv*32 + rt*16 + l16)*136 + ks*32 + quad*8);
#pragma unroll
            for (int dt = 0; dt < 4; ++dt) {
                bf16x8 bvv = *(const bf16x8*)(Vs + (dt*16 + l16)*136 + ks*32 + quad*8);
#pragma unroll
                for (int rt = 0; rt < 2; ++rt)
                    acc_o[rt][dt] = __builtin_amdgcn_mfma_f32_16x16x32_bf16(
                        ap[rt], bvv, acc_o[rt][dt], 0, 0, 0);
            }
        }
    }

    const int b = bh >> 4, h = bh & 15;
#pragma unroll
    for (int rt = 0; rt < 2; ++rt) {
#pragma unroll
        for (int r = 0; r < 4; ++r) {
            const float inv = 1.f / __shfl(l_run[rt], quad*4 + r, 16);
            const int m = qt*128 + wv*32 + rt*16 + quad*4 + r;
#pragma unroll
            for (int dt = 0; dt < 4; ++dt) {
                const int d = dt*16 + l16;
                O[((size_t)b*1024 + m)*1024 + h*64 + d] =
                    (bf16_t)(acc_o[rt][dt][r] * inv);
            }
        }
    }
}

// ---------------------------------------------------------------------------
extern "C" void kernel_launch(void* const* d_in, const int* in_sizes, int n_in,
                              void* d_out, int out_size, void* d_ws, size_t ws_size,
                              hipStream_t stream)
{
    (void)in_sizes; (void)n_in;
    const size_t MB = 1ull << 20;
    if (ws_size < 64 * MB) {
        hipMemsetAsync(d_out, 0, (size_t)out_size * sizeof(float), stream);
        return;
    }

    const float* x  = (const float*)d_in[0];
    const float* g1 = (const float*)d_in[1];
    const float* b1 = (const float*)d_in[2];
    const float* Wq = (const float*)d_in[3];
    const float* bq = (const float*)d_in[4];
    const float* Wk = (const float*)d_in[5];
    const float* bk = (const float*)d_in[6];
    const float* Wv = (const float*)d_in[7];
    const float* bv = (const float*)d_in[8];
    const float* Wp = (const float*)d_in[9];
    const float* bp = (const float*)d_in[10];
    const float* g2 = (const float*)d_in[11];
    const float* b2 = (const float*)d_in[12];
    const float* W1 = (const float*)d_in[13];
    const float* c1 = (const float*)d_in[14];
    const float* W2 = (const float*)d_in[15];
    const float* c2 = (const float*)d_in[16];

    char* ws = (char*)d_ws;
    bf16_t* Kb  = (bf16_t*)(ws);
    bf16_t* Vb  = (bf16_t*)(ws + 16 * MB);
    bf16_t* Cs  = (bf16_t*)(ws + 32 * MB);
    bf16_t* WqT = (bf16_t*)(ws + 48 * MB);
    bf16_t* WpT = (bf16_t*)(ws + 54 * MB);
    bf16_t* W1T = (bf16_t*)(ws + 56 * MB);
    bf16_t* W2T = (bf16_t*)(ws + 48 * MB);   // after WqkvT/WpT dead
    bf16_t* Qb  = (bf16_t*)d_out;
    bf16_t* Ob  = Vb;
    bf16_t* hid = Kb;                        // 32 MB spanning S0+S1
    bf16_t* h2  = Cs;
    float*  x2  = (float*)d_out;
    float*  outf = (float*)d_out;

    const dim3 blk(256);
    const dim3 blk5(512);

    // weight transposes (f32 -> bf16, (N,K)); Wq/Wk/Wv land contiguous
    transpose_f32_bf16<<<dim3(16, 16, 1), blk, 0, stream>>>(Wq, WqT,              1024, 1024, 0, 0);
    transpose_f32_bf16<<<dim3(16, 16, 1), blk, 0, stream>>>(Wk, WqT + 1024*1024,  1024, 1024, 0, 0);
    transpose_f32_bf16<<<dim3(16, 16, 1), blk, 0, stream>>>(Wv, WqT + 2*1024*1024, 1024, 1024, 0, 0);
    transpose_f32_bf16<<<dim3(16, 16, 1), blk, 0, stream>>>(Wp, WpT,              1024, 1024, 0, 0);
    transpose_f32_bf16<<<dim3(64, 16, 1), blk, 0, stream>>>(W1, W1T,              1024, 4096, 0, 0);

    // LN1: x -> h1 (Cs)
    ln_kernel<<<8192, blk, 0, stream>>>(x, g1, b1, Cs);

    // fused QKV: BN=128 -> 768 blocks = 3 perfectly balanced rounds
    gemm256<0, 128><<<dim3(32, 24), blk5, 0, stream>>>(
        Cs, WqT, bq, bk, bv, nullptr, Qb, Kb, Vb, nullptr, 3072, 1024);

    // per-head V transpose: V(S1) -> Vt(S2)
    transpose_bf16<<<dim3(1, 16, 128), blk, 0, stream>>>(Vb, Cs, 1024, 64, 65536, 65536);

    // flash attention: Q(d_out), K(S0), Vt(S2) -> Ob(S1)
    attn_kernel<<<dim3(8, 128), blk, 0, stream>>>(Qb, Kb, Cs, Ob);

    // proj + residual: BN=128 -> 256 blocks (full machine)
    gemm256<1, 128><<<dim3(32, 8), blk5, 0, stream>>>(
        Ob, WpT, bp, nullptr, nullptr, x, nullptr, nullptr, nullptr, x2, 1024, 1024);

    // W2 -> 2 K-chunks (1024 x 2048 each), into dead weights arena @48-56
    transpose_f32_bf16<<<dim3(16, 32, 2), blk, 0, stream>>>(
        W2, W2T, 2048, 1024, 2048*1024, 2048*1024);

    // LN2: x2 -> h2 (Cs)
    ln_kernel<<<8192, blk, 0, stream>>>(x2, g2, b2, h2);

    // MLP: fc1 chunks at BN=256 (grid 256, full machine); fc2 at BN=128
    for (int c = 0; c < 2; ++c) {
        gemm256<2, 256><<<dim3(32, 8), blk5, 0, stream>>>(
            h2, W1T + (size_t)c * 2048 * 1024, c1 + c * 2048,
            nullptr, nullptr, nullptr, hid, nullptr, nullptr, nullptr, 2048, 1024);
        if (c == 0)
            gemm256<1, 128><<<dim3(32, 8), blk5, 0, stream>>>(
                hid, W2T, c2, nullptr, nullptr, outf,
                nullptr, nullptr, nullptr, outf, 1024, 2048);
        else
            gemm256<5, 128><<<dim3(32, 8), blk5, 0, stream>>>(
                hid, W2T + (size_t)2048 * 1024, nullptr, nullptr, nullptr, nullptr,
                nullptr, nullptr, nullptr, outf, 1024, 2048);
    }
}